// Round 10
// baseline (609.608 us; speedup 1.0000x reference)
//
#include <hip/hip_runtime.h>

// LSTM_76622216560744: 2-layer LSTM (H=50), B=2048, T=1024, input dim 1.
// R10: fp16 MFMA (16x16x32_f16), M=200 gate rows (row'=unit*4+type), N=16
// (8 real batches), combined K=128 B-operand [x | h1 | h2 | pad].
// NEW: 8 waves (NT=512, 2/SIMD), waves 0-4 own TWO tiles {w, w+8}, waves
// 5-7 one tile -> DS reads/step 52->32 (each B-frag feeds 2 tiles) and
// ILP-2 on the MFMA + update chains replaces the lost TLP. Weights/biases
// pre-scaled by -log2e (-2log2e for g rows) -> raw v_exp. L1/L2 acc merge
// via update_dpp (row_shr:8, bank_mask=0xC). Unconditional updates; invalid
// lanes dump to slots 2048+L (outside k<128 read region). x staged by wave
// 7's low lanes. Double-buffered v, 1 barrier/step.

#define TT 1024
#define HH 50
#define NB 8     // real batches per block
#define NT 512   // 8 waves, 2 per SIMD
#define VSZ 2112 // 2048 data shorts + 64 dump shorts

typedef _Float16 f16x8 __attribute__((ext_vector_type(8)));
typedef unsigned short ushort8 __attribute__((ext_vector_type(8)));
typedef float f32x4 __attribute__((ext_vector_type(4)));

#define NLOG2E  -1.4426950408889634f   // -log2(e)
#define N2LOG2E -2.8853900817779268f   // -2*log2(e)

__device__ __forceinline__ float fast_rcp(float x) { return __builtin_amdgcn_rcpf(x); }
__device__ __forceinline__ float exp2f_hw(float x) { return __builtin_amdgcn_exp2f(x); }
__device__ __forceinline__ unsigned short f16bits(float f) {
    _Float16 h = (_Float16)f;                 // v_cvt_f16_f32 (RNE)
    return __builtin_bit_cast(unsigned short, h);
}
__device__ __forceinline__ float f16tof(unsigned short b) {
    return (float)__builtin_bit_cast(_Float16, b);
}
// merge: per 16-lane row, lanes 0..7 keep a (L1 acc), lanes 8..15 take
// lanes 0..7's b (L2 acc). row_shr:8 = 0x118; bank_mask 0xC = banks 2,3.
__device__ __forceinline__ float dpp_merge(float a, float b) {
    return __int_as_float(__builtin_amdgcn_update_dpp(
        __float_as_int(a), __float_as_int(b), 0x118, 0xF, 0xC, false));
}

// frag-ready blocked layout: idx = (k>>3)*128 + n*8 + (k&7), k<128, n<16
__device__ __forceinline__ int vidx(int k, int n) {
    return ((k >> 3) << 7) + n * 8 + (k & 7);
}

__global__ __launch_bounds__(NT, 2) void lstm_kernel(
    const float* __restrict__ x,
    const float* __restrict__ W_ih1, const float* __restrict__ W_hh1,
    const float* __restrict__ b_ih1, const float* __restrict__ b_hh1,
    const float* __restrict__ W_ih2, const float* __restrict__ W_hh2,
    const float* __restrict__ b_ih2, const float* __restrict__ b_hh2,
    const float* __restrict__ W_lin, const float* __restrict__ b_lin,
    float* __restrict__ out)
{
    __shared__ float xs[TT * NB];                                     // 32 KB
    __shared__ __attribute__((aligned(16))) unsigned short v[2][VSZ]; // 8.25 KB

    const int tid  = threadIdx.x;
    const int w    = tid >> 6;       // wave 0..7
    const int L    = tid & 63;
    const int quad = L >> 4;
    const int n15  = L & 15;
    const int b0g  = blockIdx.x * NB;

    const int  np   = (w < 5) ? 2 : 1;   // tiles this wave owns: {w} or {w, w+8}
    const bool low  = (n15 < NB);        // low half: L1 / B loads
    const bool ldB  = low;
    // wave 7's low lanes stage x(t+1) (it has only 1 tile -> spare slack)
    const bool xw   = (w == 7) && (L < NB);

    int  mA[2];  mA[0] = w;  mA[1] = w + 8;
    int  hslot[2];
    bool updOK[2];
    #pragma unroll
    for (int p = 0; p < 2; ++p) {
        int u = mA[p] * 4 + quad;
        updOK[p] = (u < HH);
        hslot[p] = updOK[p] ? (low ? vidx(1 + u, n15) : vidx(51 + u, n15 - NB))
                            : (2048 + L);
    }

    for (int i = tid; i < 2 * VSZ; i += NT) ((unsigned short*)v)[i] = 0;
    for (int i = tid; i < NB * TT; i += NT) {   // stage x transposed xs[t][b]
        int b = i >> 10, t = i & 1023;
        xs[t * NB + b] = x[(size_t)b0g * TT + i];
    }

    // ---- per-wave A-frags (up to 2 tiles): fp16, pre-scaled by -log2e ----
    f16x8 a1[2][2], a2[2][4];
    f32x4 bias1[2], bias2[2];
    float c[2] = {0.f, 0.f};   // per tile; low lanes: c1, high lanes: c2

    #pragma unroll
    for (int p = 0; p < 2; ++p) {
        const int m = mA[p];
        const bool pv = (p < np);
        const int arow = m * 16 + n15;
        const bool av = pv && (arow < 200);
        const int r = av ? ((arow & 3) * 50 + (arow >> 2)) : 0;  // type*50+unit
        const float sc = ((arow & 3) == 2) ? N2LOG2E : NLOG2E;
        #pragma unroll
        for (int kt = 0; kt < 2; ++kt) {    // L1 A: k=0 -> W_ih1, k in [1,50] -> W_hh1
            ushort8 th;
            #pragma unroll
            for (int j = 0; j < 8; ++j) {
                int k = kt * 32 + quad * 8 + j;
                float wv = 0.f;
                if (av) { if (k == 0) wv = W_ih1[r]; else if (k <= 50) wv = W_hh1[r * 50 + k - 1]; }
                th[j] = f16bits(wv * sc);
            }
            a1[p][kt] = __builtin_bit_cast(f16x8, th);
        }
        #pragma unroll
        for (int kt = 0; kt < 4; ++kt) {    // L2 A: k 1..50 -> W_ih2, 51..100 -> W_hh2
            ushort8 th;
            #pragma unroll
            for (int j = 0; j < 8; ++j) {
                int k = kt * 32 + quad * 8 + j;
                float wv = 0.f;
                if (av) {
                    if (k >= 1 && k <= 50) wv = W_ih2[r * 50 + k - 1];
                    else if (k >= 51 && k <= 100) wv = W_hh2[r * 50 + k - 51];
                }
                th[j] = f16bits(wv * sc);
            }
            a2[p][kt] = __builtin_bit_cast(f16x8, th);
        }
        f32x4 bb1 = {0.f,0.f,0.f,0.f}, bb2 = {0.f,0.f,0.f,0.f};
        #pragma unroll
        for (int reg = 0; reg < 4; ++reg) {
            int crow = m * 16 + quad * 4 + reg;
            if (pv && crow < 200) {
                int rr = (crow & 3) * 50 + (crow >> 2);
                float s2 = ((crow & 3) == 2) ? N2LOG2E : NLOG2E;
                bb1[reg] = s2 * (b_ih1[rr] + b_hh1[rr]);
                bb2[reg] = s2 * (b_ih2[rr] + b_hh2[rr]);
            }
        }
        bias1[p] = bb1; bias2[p] = bb2;
    }

    __syncthreads();
    if (tid < NB) v[0][vidx(0, tid)] = f16bits(xs[0 * NB + tid]);  // x(0)
    __syncthreads();

    f16x8 bfr[4];
    #pragma unroll
    for (int kt = 0; kt < 4; ++kt)
        bfr[kt] = __builtin_bit_cast(f16x8, ushort8{0,0,0,0,0,0,0,0});

    // one step: iter t = L1 gates(t) + L2 gates(t-1); read vr, write vw.
    auto body = [&](int t, const unsigned short* vr, unsigned short* vw,
                    bool doL1, bool doL2, bool masked) {
        if (ldB) {
            #pragma unroll
            for (int kt = 0; kt < 4; ++kt)
                bfr[kt] = ((const f16x8*)vr)[kt * 64 + L];
        }
        f32x4 aM1[2], aM2[2];
        #pragma unroll
        for (int p = 0; p < 2; ++p) { aM1[p] = bias1[p]; aM2[p] = bias2[p]; }
        if (doL1) {
            #pragma unroll
            for (int kt = 0; kt < 2; ++kt)
                #pragma unroll
                for (int p = 0; p < 2; ++p) if (p < np)
                    aM1[p] = __builtin_amdgcn_mfma_f32_16x16x32_f16(a1[p][kt], bfr[kt], aM1[p], 0, 0, 0);
        }
        if (doL2) {
            #pragma unroll
            for (int kt = 0; kt < 4; ++kt)
                #pragma unroll
                for (int p = 0; p < 2; ++p) if (p < np)
                    aM2[p] = __builtin_amdgcn_mfma_f32_16x16x32_f16(a2[p][kt], bfr[kt], aM2[p], 0, 0, 0);
        }
        // merge + interleaved update chains (independent registers -> ILP-2)
        #pragma unroll
        for (int p = 0; p < 2; ++p) if (p < np) {
            f32x4 g;
            #pragma unroll
            for (int r = 0; r < 4; ++r) g[r] = dpp_merge(aM1[p][r], aM2[p][r]);
            if (!masked || (updOK[p] && low)) {
                float ei = exp2f_hw(g[0]);           // e^-i
                float ef = exp2f_hw(g[1]);           // e^-f
                float eg = exp2f_hw(g[2]);           // e^-2gg
                float eo = exp2f_hw(g[3]);           // e^-o
                float pp = (1.0f + ei) * (1.0f + eg);
                float qq = (1.0f - eg) * (1.0f + ef);
                float cn = fmaf(c[p], pp, qq) * fast_rcp(pp * (1.0f + ef));
                c[p] = cn;
                float ecn = exp2f_hw(cn * N2LOG2E);  // e^-2c
                float h = (1.0f - ecn) * fast_rcp((1.0f + eo) * (1.0f + ecn));
                vw[hslot[p]] = f16bits(h);
            }
        }
        if (xw && t + 1 < TT) vw[vidx(0, L)] = f16bits(xs[(t + 1) * NB + L]);
        __syncthreads();
    };

    // peel t=0 (no L2 yet: masked update protects high-half c), steady, tail.
    body(0, v[0], v[1], true, false, true);
    body(1, v[1], v[0], true, true, false);
    for (int t = 2; t < TT; t += 2) {
        body(t,     v[0], v[1], true, true, false);
        body(t + 1, v[1], v[0], true, true, false);
    }
    // tail: L2 gates(TT-1) only; low-half h1/c1 writes are dead
    body(TT, v[0], v[1], false, true, false);

    // epilogue: h2(T-1) sits in buf1 slots 51..100
    if (tid < NB) {
        float s = b_lin[0];
        #pragma unroll
        for (int uu = 0; uu < HH; ++uu)
            s += W_lin[uu] * f16tof(v[1][vidx(51 + uu, tid)]);
        out[b0g + tid] = s;
    }
}

extern "C" void kernel_launch(void* const* d_in, const int* in_sizes, int n_in,
                              void* d_out, int out_size, void* d_ws, size_t ws_size,
                              hipStream_t stream) {
    const float* x     = (const float*)d_in[0];
    const float* W_ih1 = (const float*)d_in[1];
    const float* W_hh1 = (const float*)d_in[2];
    const float* b_ih1 = (const float*)d_in[3];
    const float* b_hh1 = (const float*)d_in[4];
    const float* W_ih2 = (const float*)d_in[5];
    const float* W_hh2 = (const float*)d_in[6];
    const float* b_ih2 = (const float*)d_in[7];
    const float* b_hh2 = (const float*)d_in[8];
    const float* W_lin = (const float*)d_in[9];
    const float* b_lin = (const float*)d_in[10];
    float* out = (float*)d_out;

    const int Btot = in_sizes[0] / TT;   // 2048
    const int nblocks = Btot / NB;       // 256 -> 1 block/CU

    lstm_kernel<<<nblocks, NT, 0, stream>>>(
        x, W_ih1, W_hh1, b_ih1, b_hh1, W_ih2, W_hh2, b_ih2, b_hh2,
        W_lin, b_lin, out);
}

// Round 11
// 601.868 us; speedup vs baseline: 1.0129x; 1.0129x over previous
//
#include <hip/hip_runtime.h>

// LSTM_76622216560744: 2-layer LSTM (H=50), B=2048, T=1024, input dim 1.
// R11 = R9 (13 waves, one tile/wave — measured-best TLP) + critical-path
// trims: L2's 4-deep dependent MFMA chain split into two independent
// 2-chains (+v_add merge), interleaved with L1's 2-chain -> MFMA-phase
// latency ~halved. fp16 MFMA (16x16x32_f16), M=200 gate rows
// (row'=unit*4+type), N=16 (8 real batches), combined K=128 B-operand
// [x | h1 | h2 | pad]. Weights/biases pre-scaled by -log2e (-2log2e for g
// rows) -> raw v_exp. L1/L2 acc merge via update_dpp (row_shr:8,
// bank_mask=0xC). Unconditional updates; invalid lanes dump to 2048+L.
// x staged by wave 12's quad-2 lanes. Double-buffered v, 1 barrier/step.

#define TT 1024
#define HH 50
#define NB 8     // real batches per block
#define NT 832   // 13 waves
#define VSZ 2112 // 2048 data shorts + 64 dump shorts

typedef _Float16 f16x8 __attribute__((ext_vector_type(8)));
typedef unsigned short ushort8 __attribute__((ext_vector_type(8)));
typedef float f32x4 __attribute__((ext_vector_type(4)));

#define NLOG2E  -1.4426950408889634f   // -log2(e)
#define N2LOG2E -2.8853900817779268f   // -2*log2(e)

__device__ __forceinline__ float fast_rcp(float x) { return __builtin_amdgcn_rcpf(x); }
__device__ __forceinline__ float exp2f_hw(float x) { return __builtin_amdgcn_exp2f(x); }
__device__ __forceinline__ unsigned short f16bits(float f) {
    _Float16 h = (_Float16)f;                 // v_cvt_f16_f32 (RNE)
    return __builtin_bit_cast(unsigned short, h);
}
__device__ __forceinline__ float f16tof(unsigned short b) {
    return (float)__builtin_bit_cast(_Float16, b);
}
// merge: per 16-lane row, lanes 0..7 keep a (L1 acc), lanes 8..15 take
// lanes 0..7's b (L2 acc). row_shr:8 = 0x118; bank_mask 0xC = banks 2,3.
__device__ __forceinline__ float dpp_merge(float a, float b) {
    return __int_as_float(__builtin_amdgcn_update_dpp(
        __float_as_int(a), __float_as_int(b), 0x118, 0xF, 0xC, false));
}

// frag-ready blocked layout: idx = (k>>3)*128 + n*8 + (k&7), k<128, n<16
__device__ __forceinline__ int vidx(int k, int n) {
    return ((k >> 3) << 7) + n * 8 + (k & 7);
}

__global__ __launch_bounds__(NT) void lstm_kernel(
    const float* __restrict__ x,
    const float* __restrict__ W_ih1, const float* __restrict__ W_hh1,
    const float* __restrict__ b_ih1, const float* __restrict__ b_hh1,
    const float* __restrict__ W_ih2, const float* __restrict__ W_hh2,
    const float* __restrict__ b_ih2, const float* __restrict__ b_hh2,
    const float* __restrict__ W_lin, const float* __restrict__ b_lin,
    float* __restrict__ out)
{
    __shared__ float xs[TT * NB];                                     // 32 KB
    __shared__ __attribute__((aligned(16))) unsigned short v[2][VSZ]; // 8.25 KB

    const int tid  = threadIdx.x;
    const int w    = tid >> 6;       // wave 0..12
    const int L    = tid & 63;
    const int quad = L >> 4;
    const int n15  = L & 15;
    const int b0g  = blockIdx.x * NB;

    const int  m     = w;                // tile per wave
    const int  u     = m * 4 + quad;     // unit this lane updates
    const bool low   = (n15 < NB);       // low half: L1 / B loads
    const bool updOK = (u < HH);
    const bool ldB   = low;
    // wave 12's quad-2 lanes (u=50, update-invalid) stage x(t+1)
    const bool xw    = (w == 12) && (L >= 32) && (L < 32 + NB);
    const int  xb    = L - 32;
    // h slot: low -> h1 (k=1+u), high -> h2 (k=51+u); invalid u -> dump tail
    const int hslot = updOK ? (low ? vidx(1 + u, n15) : vidx(51 + u, n15 - NB))
                            : (2048 + L);

    for (int i = tid; i < 2 * VSZ; i += NT) ((unsigned short*)v)[i] = 0;
    for (int i = tid; i < NB * TT; i += NT) {   // stage x transposed xs[t][b]
        int b = i >> 10, t = i & 1023;
        xs[t * NB + b] = x[(size_t)b0g * TT + i];
    }

    // ---- per-wave A-frags: fp16, pre-scaled by -log2e (g rows: -2log2e) ----
    f16x8 a1[2], a2[4];
    f32x4 bias1 = {0.f, 0.f, 0.f, 0.f}, bias2 = {0.f, 0.f, 0.f, 0.f};
    float c = 0.f;    // low lanes: c1, high lanes: c2

    {
        const int arow = m * 16 + n15;
        const bool av = (arow < 200);
        const int r = av ? ((arow & 3) * 50 + (arow >> 2)) : 0;  // type*50+unit
        const float sc = ((arow & 3) == 2) ? N2LOG2E : NLOG2E;
        #pragma unroll
        for (int kt = 0; kt < 2; ++kt) {    // L1 A: k=0 -> W_ih1, k in [1,50] -> W_hh1
            ushort8 th;
            #pragma unroll
            for (int j = 0; j < 8; ++j) {
                int k = kt * 32 + quad * 8 + j;
                float wv = 0.f;
                if (av) { if (k == 0) wv = W_ih1[r]; else if (k <= 50) wv = W_hh1[r * 50 + k - 1]; }
                th[j] = f16bits(wv * sc);
            }
            a1[kt] = __builtin_bit_cast(f16x8, th);
        }
        #pragma unroll
        for (int kt = 0; kt < 4; ++kt) {    // L2 A: k 1..50 -> W_ih2, 51..100 -> W_hh2
            ushort8 th;
            #pragma unroll
            for (int j = 0; j < 8; ++j) {
                int k = kt * 32 + quad * 8 + j;
                float wv = 0.f;
                if (av) {
                    if (k >= 1 && k <= 50) wv = W_ih2[r * 50 + k - 1];
                    else if (k >= 51 && k <= 100) wv = W_hh2[r * 50 + k - 51];
                }
                th[j] = f16bits(wv * sc);
            }
            a2[kt] = __builtin_bit_cast(f16x8, th);
        }
        #pragma unroll
        for (int reg = 0; reg < 4; ++reg) {
            int crow = m * 16 + quad * 4 + reg;
            if (crow < 200) {
                int rr = (crow & 3) * 50 + (crow >> 2);
                float s2 = ((crow & 3) == 2) ? N2LOG2E : NLOG2E;
                bias1[reg] = s2 * (b_ih1[rr] + b_hh1[rr]);
                bias2[reg] = s2 * (b_ih2[rr] + b_hh2[rr]);
            }
        }
    }

    __syncthreads();
    if (tid < NB) v[0][vidx(0, tid)] = f16bits(xs[0 * NB + tid]);  // x(0)
    __syncthreads();

    f16x8 bfr[4];
    #pragma unroll
    for (int kt = 0; kt < 4; ++kt)
        bfr[kt] = __builtin_bit_cast(f16x8, ushort8{0,0,0,0,0,0,0,0});

    const f32x4 zero4 = {0.f, 0.f, 0.f, 0.f};

    // one step: iter t = L1 gates(t) + L2 gates(t-1); read vr, write vw.
    // Accumulators hold -g*log2e (g rows: -2g*log2e) -> raw v_exp gives e^-g.
    auto body = [&](int t, const unsigned short* vr, unsigned short* vw,
                    bool doL1, bool doL2, bool masked) {
        if (ldB) {
            // kt0/kt1 first: L1 + L2a chains start at lgkmcnt(2)
            bfr[0] = ((const f16x8*)vr)[0 * 64 + L];
            bfr[1] = ((const f16x8*)vr)[1 * 64 + L];
            bfr[2] = ((const f16x8*)vr)[2 * 64 + L];
            bfr[3] = ((const f16x8*)vr)[3 * 64 + L];
        }
        // three independent 2-deep MFMA chains, interleaved
        f32x4 aM1 = bias1, aM2a = bias2, aM2b = zero4;
        if (doL1) aM1  = __builtin_amdgcn_mfma_f32_16x16x32_f16(a1[0], bfr[0], aM1, 0, 0, 0);
        if (doL2) aM2a = __builtin_amdgcn_mfma_f32_16x16x32_f16(a2[0], bfr[0], aM2a, 0, 0, 0);
        if (doL2) aM2b = __builtin_amdgcn_mfma_f32_16x16x32_f16(a2[2], bfr[2], aM2b, 0, 0, 0);
        if (doL1) aM1  = __builtin_amdgcn_mfma_f32_16x16x32_f16(a1[1], bfr[1], aM1, 0, 0, 0);
        if (doL2) aM2a = __builtin_amdgcn_mfma_f32_16x16x32_f16(a2[1], bfr[1], aM2a, 0, 0, 0);
        if (doL2) aM2b = __builtin_amdgcn_mfma_f32_16x16x32_f16(a2[3], bfr[3], aM2b, 0, 0, 0);
        f32x4 aM2 = aM2a + aM2b;

        // merge: low 8 of each 16-row keep L1 acc, high 8 take partner L2 acc
        f32x4 g;
        #pragma unroll
        for (int r = 0; r < 4; ++r) g[r] = dpp_merge(aM1[r], aM2[r]);

        // cell update: g = (-i, -f, -2gg, -o)*log2e; single-rcp cn
        if (!masked || (updOK && low)) {
            float ei = exp2f_hw(g[0]);           // e^-i
            float ef = exp2f_hw(g[1]);           // e^-f
            float eg = exp2f_hw(g[2]);           // e^-2gg
            float eo = exp2f_hw(g[3]);           // e^-o
            float p  = (1.0f + ei) * (1.0f + eg);
            float q  = (1.0f - eg) * (1.0f + ef);
            float cn = fmaf(c, p, q) * fast_rcp(p * (1.0f + ef));
            c = cn;
            float ecn = exp2f_hw(cn * N2LOG2E);  // e^-2c
            float h = (1.0f - ecn) * fast_rcp((1.0f + eo) * (1.0f + ecn));
            vw[hslot] = f16bits(h);
        }
        if (xw && t + 1 < TT) vw[vidx(0, xb)] = f16bits(xs[(t + 1) * NB + xb]);
        __syncthreads();
    };

    // peel t=0 (no L2 yet: masked update protects high-half c), steady, tail.
    body(0, v[0], v[1], true, false, true);
    body(1, v[1], v[0], true, true, false);
    for (int t = 2; t < TT; t += 2) {
        body(t,     v[0], v[1], true, true, false);
        body(t + 1, v[1], v[0], true, true, false);
    }
    // tail: L2 gates(TT-1) only; low-half h1/c1 writes are dead
    body(TT, v[0], v[1], false, true, false);

    // epilogue: h2(T-1) sits in buf1 slots 51..100
    if (tid < NB) {
        float s = b_lin[0];
        #pragma unroll
        for (int uu = 0; uu < HH; ++uu)
            s += W_lin[uu] * f16tof(v[1][vidx(51 + uu, tid)]);
        out[b0g + tid] = s;
    }
}

extern "C" void kernel_launch(void* const* d_in, const int* in_sizes, int n_in,
                              void* d_out, int out_size, void* d_ws, size_t ws_size,
                              hipStream_t stream) {
    const float* x     = (const float*)d_in[0];
    const float* W_ih1 = (const float*)d_in[1];
    const float* W_hh1 = (const float*)d_in[2];
    const float* b_ih1 = (const float*)d_in[3];
    const float* b_hh1 = (const float*)d_in[4];
    const float* W_ih2 = (const float*)d_in[5];
    const float* W_hh2 = (const float*)d_in[6];
    const float* b_ih2 = (const float*)d_in[7];
    const float* b_hh2 = (const float*)d_in[8];
    const float* W_lin = (const float*)d_in[9];
    const float* b_lin = (const float*)d_in[10];
    float* out = (float*)d_out;

    const int Btot = in_sizes[0] / TT;   // 2048
    const int nblocks = Btot / NB;       // 256 -> 1 block/CU

    lstm_kernel<<<nblocks, NT, 0, stream>>>(
        x, W_ih1, W_hh1, b_ih1, b_hh1, W_ih2, W_hh2, b_ih2, b_hh2,
        W_lin, b_lin, out);
}

// Round 12
// 534.333 us; speedup vs baseline: 1.1409x; 1.1264x over previous
//
#include <hip/hip_runtime.h>

// LSTM_76622216560744: 2-layer LSTM (H=50), B=2048, T=1024, input dim 1.
// R12 = R9 verbatim (measured best: 534 us). 13 waves, one M-tile/wave.
// fp16 MFMA (16x16x32_f16), M=200 gate rows (row'=unit*4+type), N=16
// (8 real batches), combined K=128 B-operand [x | h1 | h2 | pad]. Weights/
// biases pre-scaled by -log2e (-2log2e for g rows) -> raw v_exp. L1/L2 acc
// merge via ONE update_dpp (row_shr:8, bank_mask=0xC). Unconditional
// updates; invalid lanes dump to slots 2048+L (outside k<128 read region).
// Single-rcp cn (5 exp + 2 rcp — algebraic minimum). Double-buffered v,
// 1 barrier/step (irreducible: h(t) is all-to-all consumed at t+1).
// R10 (2 waves/SIMD + ILP-2) and R11 (chain-split ILP) both measured
// slower — TLP at 3.25 waves/SIMD is the binding resource and it already
// hides MFMA chain latency.

#define TT 1024
#define HH 50
#define NB 8     // real batches per block
#define NT 832   // 13 waves
#define VSZ 2112 // 2048 data shorts + 64 dump shorts

typedef _Float16 f16x8 __attribute__((ext_vector_type(8)));
typedef unsigned short ushort8 __attribute__((ext_vector_type(8)));
typedef float f32x4 __attribute__((ext_vector_type(4)));

#define NLOG2E  -1.4426950408889634f   // -log2(e)
#define N2LOG2E -2.8853900817779268f   // -2*log2(e)

__device__ __forceinline__ float fast_rcp(float x) { return __builtin_amdgcn_rcpf(x); }
__device__ __forceinline__ float exp2f_hw(float x) { return __builtin_amdgcn_exp2f(x); }
__device__ __forceinline__ unsigned short f16bits(float f) {
    _Float16 h = (_Float16)f;                 // v_cvt_f16_f32 (RNE)
    return __builtin_bit_cast(unsigned short, h);
}
__device__ __forceinline__ float f16tof(unsigned short b) {
    return (float)__builtin_bit_cast(_Float16, b);
}
// merge: per 16-lane row, lanes 0..7 keep a (L1 acc), lanes 8..15 take
// lanes 0..7's b (L2 acc). row_shr:8 = 0x118; bank_mask 0xC = banks 2,3.
__device__ __forceinline__ float dpp_merge(float a, float b) {
    return __int_as_float(__builtin_amdgcn_update_dpp(
        __float_as_int(a), __float_as_int(b), 0x118, 0xF, 0xC, false));
}

// frag-ready blocked layout: idx = (k>>3)*128 + n*8 + (k&7), k<128, n<16
__device__ __forceinline__ int vidx(int k, int n) {
    return ((k >> 3) << 7) + n * 8 + (k & 7);
}

__global__ __launch_bounds__(NT) void lstm_kernel(
    const float* __restrict__ x,
    const float* __restrict__ W_ih1, const float* __restrict__ W_hh1,
    const float* __restrict__ b_ih1, const float* __restrict__ b_hh1,
    const float* __restrict__ W_ih2, const float* __restrict__ W_hh2,
    const float* __restrict__ b_ih2, const float* __restrict__ b_hh2,
    const float* __restrict__ W_lin, const float* __restrict__ b_lin,
    float* __restrict__ out)
{
    __shared__ float xs[TT * NB];                                     // 32 KB
    __shared__ __attribute__((aligned(16))) unsigned short v[2][VSZ]; // 8.25 KB

    const int tid  = threadIdx.x;
    const int w    = tid >> 6;       // wave 0..12
    const int L    = tid & 63;
    const int quad = L >> 4;
    const int n15  = L & 15;
    const int b0g  = blockIdx.x * NB;

    const int  m     = w;                // tile per wave
    const int  u     = m * 4 + quad;     // unit this lane updates
    const bool low   = (n15 < NB);       // low half: L1 / B loads
    const bool updOK = (u < HH);
    const bool ldB   = low;
    // wave 12's quad-2 lanes (u=50, update-invalid) stage x(t+1)
    const bool xw    = (w == 12) && (L >= 32) && (L < 32 + NB);
    const int  xb    = L - 32;
    // h slot: low -> h1 (k=1+u), high -> h2 (k=51+u); invalid u -> dump tail
    const int hslot = updOK ? (low ? vidx(1 + u, n15) : vidx(51 + u, n15 - NB))
                            : (2048 + L);

    for (int i = tid; i < 2 * VSZ; i += NT) ((unsigned short*)v)[i] = 0;
    for (int i = tid; i < NB * TT; i += NT) {   // stage x transposed xs[t][b]
        int b = i >> 10, t = i & 1023;
        xs[t * NB + b] = x[(size_t)b0g * TT + i];
    }

    // ---- per-wave A-frags: fp16, pre-scaled by -log2e (g rows: -2log2e) ----
    f16x8 a1[2], a2[4];
    f32x4 bias1 = {0.f, 0.f, 0.f, 0.f}, bias2 = {0.f, 0.f, 0.f, 0.f};
    float c = 0.f;    // low lanes: c1, high lanes: c2

    {
        const int arow = m * 16 + n15;
        const bool av = (arow < 200);
        const int r = av ? ((arow & 3) * 50 + (arow >> 2)) : 0;  // type*50+unit
        const float sc = ((arow & 3) == 2) ? N2LOG2E : NLOG2E;
        #pragma unroll
        for (int kt = 0; kt < 2; ++kt) {    // L1 A: k=0 -> W_ih1, k in [1,50] -> W_hh1
            ushort8 th;
            #pragma unroll
            for (int j = 0; j < 8; ++j) {
                int k = kt * 32 + quad * 8 + j;
                float wv = 0.f;
                if (av) { if (k == 0) wv = W_ih1[r]; else if (k <= 50) wv = W_hh1[r * 50 + k - 1]; }
                th[j] = f16bits(wv * sc);
            }
            a1[kt] = __builtin_bit_cast(f16x8, th);
        }
        #pragma unroll
        for (int kt = 0; kt < 4; ++kt) {    // L2 A: k 1..50 -> W_ih2, 51..100 -> W_hh2
            ushort8 th;
            #pragma unroll
            for (int j = 0; j < 8; ++j) {
                int k = kt * 32 + quad * 8 + j;
                float wv = 0.f;
                if (av) {
                    if (k >= 1 && k <= 50) wv = W_ih2[r * 50 + k - 1];
                    else if (k >= 51 && k <= 100) wv = W_hh2[r * 50 + k - 51];
                }
                th[j] = f16bits(wv * sc);
            }
            a2[kt] = __builtin_bit_cast(f16x8, th);
        }
        #pragma unroll
        for (int reg = 0; reg < 4; ++reg) {
            int crow = m * 16 + quad * 4 + reg;
            if (crow < 200) {
                int rr = (crow & 3) * 50 + (crow >> 2);
                float s2 = ((crow & 3) == 2) ? N2LOG2E : NLOG2E;
                bias1[reg] = s2 * (b_ih1[rr] + b_hh1[rr]);
                bias2[reg] = s2 * (b_ih2[rr] + b_hh2[rr]);
            }
        }
    }

    __syncthreads();
    if (tid < NB) v[0][vidx(0, tid)] = f16bits(xs[0 * NB + tid]);  // x(0)
    __syncthreads();

    f16x8 bfr[4];
    #pragma unroll
    for (int kt = 0; kt < 4; ++kt)
        bfr[kt] = __builtin_bit_cast(f16x8, ushort8{0,0,0,0,0,0,0,0});

    // one step: iter t = L1 gates(t) + L2 gates(t-1); read vr, write vw.
    // Accumulators hold -g*log2e (g rows: -2g*log2e) -> raw v_exp gives e^-g.
    auto body = [&](int t, const unsigned short* vr, unsigned short* vw,
                    bool doL1, bool doL2, bool masked) {
        if (ldB) {
            #pragma unroll
            for (int kt = 0; kt < 4; ++kt)
                bfr[kt] = ((const f16x8*)vr)[kt * 64 + L];
        }
        f32x4 aM1 = bias1, aM2 = bias2;
        if (doL1) {
            #pragma unroll
            for (int kt = 0; kt < 2; ++kt)
                aM1 = __builtin_amdgcn_mfma_f32_16x16x32_f16(a1[kt], bfr[kt], aM1, 0, 0, 0);
        }
        if (doL2) {
            #pragma unroll
            for (int kt = 0; kt < 4; ++kt)
                aM2 = __builtin_amdgcn_mfma_f32_16x16x32_f16(a2[kt], bfr[kt], aM2, 0, 0, 0);
        }
        // merge: low 8 of each 16-row keep L1 acc, high 8 take partner L2 acc
        f32x4 g;
        #pragma unroll
        for (int r = 0; r < 4; ++r) g[r] = dpp_merge(aM1[r], aM2[r]);

        // cell update: g = (-i, -f, -2gg, -o)*log2e; single-rcp cn
        if (!masked || (updOK && low)) {
            float ei = exp2f_hw(g[0]);           // e^-i
            float ef = exp2f_hw(g[1]);           // e^-f
            float eg = exp2f_hw(g[2]);           // e^-2gg
            float eo = exp2f_hw(g[3]);           // e^-o
            float p  = (1.0f + ei) * (1.0f + eg);
            float q  = (1.0f - eg) * (1.0f + ef);
            float cn = fmaf(c, p, q) * fast_rcp(p * (1.0f + ef));
            c = cn;
            float ecn = exp2f_hw(cn * N2LOG2E);  // e^-2c
            float h = (1.0f - ecn) * fast_rcp((1.0f + eo) * (1.0f + ecn));
            vw[hslot] = f16bits(h);
        }
        if (xw && t + 1 < TT) vw[vidx(0, xb)] = f16bits(xs[(t + 1) * NB + xb]);
        __syncthreads();
    };

    // peel t=0 (no L2 yet: masked update protects high-half c), steady, tail.
    body(0, v[0], v[1], true, false, true);
    body(1, v[1], v[0], true, true, false);
    for (int t = 2; t < TT; t += 2) {
        body(t,     v[0], v[1], true, true, false);
        body(t + 1, v[1], v[0], true, true, false);
    }
    // tail: L2 gates(TT-1) only; low-half h1/c1 writes are dead
    body(TT, v[0], v[1], false, true, false);

    // epilogue: h2(T-1) sits in buf1 slots 51..100
    if (tid < NB) {
        float s = b_lin[0];
        #pragma unroll
        for (int uu = 0; uu < HH; ++uu)
            s += W_lin[uu] * f16tof(v[1][vidx(51 + uu, tid)]);
        out[b0g + tid] = s;
    }
}

extern "C" void kernel_launch(void* const* d_in, const int* in_sizes, int n_in,
                              void* d_out, int out_size, void* d_ws, size_t ws_size,
                              hipStream_t stream) {
    const float* x     = (const float*)d_in[0];
    const float* W_ih1 = (const float*)d_in[1];
    const float* W_hh1 = (const float*)d_in[2];
    const float* b_ih1 = (const float*)d_in[3];
    const float* b_hh1 = (const float*)d_in[4];
    const float* W_ih2 = (const float*)d_in[5];
    const float* W_hh2 = (const float*)d_in[6];
    const float* b_ih2 = (const float*)d_in[7];
    const float* b_hh2 = (const float*)d_in[8];
    const float* W_lin = (const float*)d_in[9];
    const float* b_lin = (const float*)d_in[10];
    float* out = (float*)d_out;

    const int Btot = in_sizes[0] / TT;   // 2048
    const int nblocks = Btot / NB;       // 256 -> 1 block/CU

    lstm_kernel<<<nblocks, NT, 0, stream>>>(
        x, W_ih1, W_hh1, b_ih1, b_hh1, W_ih2, W_hh2, b_ih2, b_hh2,
        W_lin, b_lin, out);
}